// Round 18
// baseline (521.754 us; speedup 1.0000x reference)
//
#include <hip/hip_runtime.h>

typedef unsigned int u32;
typedef unsigned short u16;
using bf16x8 = __attribute__((ext_vector_type(8))) short;
using f32x4  = __attribute__((ext_vector_type(4))) float;

#define ND 50000
#define NF 50000
#define NE 800000
#define DD 64
#define NBLK 196   // ceil(50000/256)
#define EBLK 3125  // 800000/256
#define UBLK 782   // ceil(50000/64)

// ---- ws float-index layout ----
#define OFF_FLAGS 0                        // [0] = idx-is-int64
#define OFF_CNTN  64
#define OFF_CNTF  (OFF_CNTN + 50000)
#define OFF_STAN  (OFF_CNTF + 50000)       // start offsets (never mutated after scan)
#define OFF_STAF  (OFF_STAN + 50000)
#define OFF_OTHN  (OFF_STAF + 50000)
#define OFF_OTHF  (OFF_OTHN + 800000)
#define OFF_MSGN  (OFF_OTHF + 800000)      // first 1.6M floats: rankN/rankF (dead after k_epm)
#define OFF_MSGF  (OFF_MSGN + 3200000)
#define OFF_BPK   (OFF_MSGF + 3200000)     // 12288 floats: 6*4096 bf16 B-frags
                                           // [P1 | W0 | Q0 | Q1 | W1 | W2]
#define WS_FLOATS (OFF_BPK + 12288)

__device__ __forceinline__ u16 f2bf(float x){ union{u32 u;float f;}v; v.f=x; u32 r=v.u+0x7fffu+((v.u>>16)&1u); return (u16)(r>>16); }
__device__ __forceinline__ float bf2f(u16 h){ union{u32 u;float f;}v; v.u=((u32)h)<<16; return v.f; }
__device__ __forceinline__ u32 pk2(float a,float b){ return (u32)f2bf(a) | ((u32)f2bf(b)<<16); }

// vectorized index fetch (int64 path loads one uint2 instead of two stride-2 words)
__device__ __forceinline__ u32 eidx_at(const u32* __restrict__ eidx, size_t i, int I64) {
  if (I64) return ((const uint2*)eidx)[i].x;
  return eidx[i];
}

// swizzled LDS byte offset for 128B bf16 rows / 256B fp32 rows
#define LDSW(row, b)  ((row)*128 + ((b) ^ (((row)&7)<<4)))
#define LDSWF(row, b) ((row)*256 + ((b) ^ (((row)&3)<<6)))

// merged prologue: blocks [0,391) zero cnt; block 391 detects dtype; [392,488) pack B-frags
__global__ __launch_bounds__(256) void k_pre(const u32* __restrict__ idxw,
                                             int* __restrict__ flags,
                                             int* __restrict__ cnt,        // 100000 ints
                                             const float* __restrict__ P1,
                                             const float* __restrict__ W0,
                                             const float* __restrict__ Q0,
                                             const float* __restrict__ Q1,
                                             const float* __restrict__ W1,
                                             const float* __restrict__ W2,
                                             u16* __restrict__ Bpk) {
  __shared__ int cn;
  const int b = blockIdx.x;
  if (b < 391) {
    const int i = b*256 + threadIdx.x;
    if (i < 100000) cnt[i] = 0;
  } else if (b == 391) {
    if (threadIdx.x == 0) cn = 0;
    __syncthreads();
    int c = 0;
    for (int k = 0; k < 16; ++k)
      c += (idxw[2*(threadIdx.x + k*256) + 1] != 0u) ? 1 : 0;
    atomicAdd(&cn, c);
    __syncthreads();
    if (threadIdx.x == 0) flags[0] = (cn == 0) ? 1 : 0;
  } else {
    const int v = (b - 392)*256 + threadIdx.x;   // 0..24575
    const int mi = v >> 12;
    const int vv = v & 4095;
    const int f = vv >> 9, rem = vv & 511;
    const int lane = rem >> 3, j = rem & 7;
    const int kk = f >> 2, nt = f & 3;
    const int k = kk*32 + (lane>>4)*8 + j;
    const int col = nt*16 + (lane&15);
    const float* __restrict__ S = (mi==0) ? P1 : (mi==1) ? W0 : (mi==2) ? Q0
                                : (mi==3) ? Q1 : (mi==4) ? W1 : W2;
    Bpk[v] = f2bf(S[k*64 + col]);
  }
}

// histogram + per-edge rank capture
__global__ __launch_bounds__(256) void k_hist2(const u32* __restrict__ eidx,
                                               int* __restrict__ cntN,
                                               int* __restrict__ cntF,
                                               int* __restrict__ rankN,
                                               int* __restrict__ rankF,
                                               const int* __restrict__ flags) {
  const int e = blockIdx.x*256 + threadIdx.x;
  const int I64 = flags[0];
  const u32 src = eidx_at(eidx, (size_t)e, I64);
  const u32 dst = eidx_at(eidx, (size_t)NE + e, I64);
  rankN[e] = atomicAdd(cntN + src, 1);
  rankF[e] = atomicAdd(cntF + dst, 1);
}

__global__ __launch_bounds__(1024) void k_scan(const int* __restrict__ cnt,
                                               int* __restrict__ sta) {
  const int base = blockIdx.x * 50000;
  const int t = threadIdx.x;
  __shared__ int part[1024];
  int local[49];
  int s = 0;
  const int start = t * 49;
  #pragma unroll
  for (int j = 0; j < 49; ++j) {
    const int idx = start + j;
    const int v = (idx < 50000) ? cnt[base + idx] : 0;
    local[j] = s;
    s += v;
  }
  part[t] = s;
  __syncthreads();
  for (int off = 1; off < 1024; off <<= 1) {
    int v = 0;
    if (t >= off) v = part[t - off];
    __syncthreads();
    if (t >= off) part[t] += v;
    __syncthreads();
  }
  const int bv = (t > 0) ? part[t - 1] : 0;
  #pragma unroll
  for (int j = 0; j < 49; ++j) {
    const int idx = start + j;
    if (idx < 50000) sta[base + idx] = bv + local[j];
  }
}

// merged proj: blocks [0,196) feat->Fp, [196,392) node->Np
__global__ __launch_bounds__(256) void k_proj2(const float* __restrict__ feat,
                                               const float* __restrict__ node,
                                               const float* __restrict__ wt,
                                               u16* __restrict__ Fp,
                                               u16* __restrict__ Np) {
  const bool isF = blockIdx.x < NBLK;
  const int row = (isF ? (int)blockIdx.x : (int)blockIdx.x - NBLK)*256 + threadIdx.x;
  if (row >= 50000) return;
  const float* __restrict__ emb = isF ? feat : node;
  u16* __restrict__ outp = isF ? Fp : Np;
  float acc[DD];
  #pragma unroll
  for (int c = 0; c < DD; ++c) acc[c] = 0.f;
  #pragma unroll 4
  for (int k4 = 0; k4 < 16; ++k4) {
    const float4 v = *(const float4*)(emb + (size_t)row*DD + k4*4);
    const float f[4] = {v.x, v.y, v.z, v.w};
    const float* __restrict__ wr = wt + k4*4*DD;
    #pragma unroll
    for (int c = 0; c < DD; ++c) {
      float a = acc[c];
      #pragma unroll
      for (int j = 0; j < 4; ++j) a = fmaf(f[j], wr[j*DD + c], a);
      acc[c] = a;
    }
  }
  uint4 s[8]; u32* sw = (u32*)s;
  #pragma unroll
  for (int i = 0; i < 32; ++i) sw[i] = pk2(acc[2*i], acc[2*i+1]);
  uint4* o4 = (uint4*)(outp + (size_t)row*DD);
  #pragma unroll
  for (int i = 0; i < 8; ++i) o4[i] = s[i];
}

// MFMA ep: X(64x64)@P1 + bP -> bf16 rows scattered to CSR slots.
// Scatter-address chain hoisted above staging so its latency hides under MFMA.
__global__ __launch_bounds__(256) void k_epm(const float* __restrict__ eemb,
                                             const u32* __restrict__ eidx,
                                             const u16* __restrict__ Bpk,
                                             const float* __restrict__ bP,
                                             const int* __restrict__ staN,
                                             const int* __restrict__ staF,
                                             const int* __restrict__ rankN,
                                             const int* __restrict__ rankF,
                                             int* __restrict__ othN,
                                             int* __restrict__ othF,
                                             u16* __restrict__ epN,
                                             u16* __restrict__ epF,
                                             const int* __restrict__ flags) {
  __shared__ u16 lds[4096];
  const int t = threadIdx.x;
  const int e0 = blockIdx.x * 64;
  const int w = t >> 6, l = t & 63;
  // hoisted epilogue address chain (independent of MFMA work)
  const int lr = l >> 2, seg = l & 3;
  const int orow = w*16 + lr;
  const int e = e0 + orow;
  const int I64 = flags[0];
  const u32 src = eidx_at(eidx, (size_t)e, I64);
  const u32 dst = eidx_at(eidx, (size_t)NE + e, I64);
  const int pN = staN[src] + rankN[e];
  const int pF = staF[dst] + rankF[e];

  #pragma unroll
  for (int i = 0; i < 4; ++i) {
    const int g = i*256 + t;
    const float4 v = ((const float4*)(eemb + (size_t)e0*DD))[g];
    const int row = g >> 4;
    const int b   = (g & 15) * 8;
    *(uint2*)((char*)lds + LDSW(row, b)) = make_uint2(pk2(v.x, v.y), pk2(v.z, v.w));
  }
  __syncthreads();
  bf16x8 bf[8];
  #pragma unroll
  for (int f = 0; f < 8; ++f)
    bf[f] = *(const bf16x8*)(Bpk + (f*64 + l)*8);
  f32x4 acc[4];
  #pragma unroll
  for (int nt = 0; nt < 4; ++nt) {
    const float b = bP[nt*16 + (l&15)];
    acc[nt] = (f32x4){b, b, b, b};
  }
  const int arow = w*16 + (l&15);
  const bf16x8 a0 = *(const bf16x8*)((char*)lds + LDSW(arow, (l>>4)*16));
  const bf16x8 a1 = *(const bf16x8*)((char*)lds + LDSW(arow, 64 + (l>>4)*16));
  #pragma unroll
  for (int nt = 0; nt < 4; ++nt) {
    acc[nt] = __builtin_amdgcn_mfma_f32_16x16x32_bf16(a0, bf[nt],     acc[nt], 0, 0, 0);
    acc[nt] = __builtin_amdgcn_mfma_f32_16x16x32_bf16(a1, bf[4 + nt], acc[nt], 0, 0, 0);
  }
  #pragma unroll
  for (int nt = 0; nt < 4; ++nt) {
    #pragma unroll
    for (int r = 0; r < 4; ++r) {
      const int row = w*16 + (l>>4)*4 + r;
      const int col = nt*16 + (l&15);
      *(u16*)((char*)lds + LDSW(row, col*2)) = f2bf(acc[nt][r]);
    }
  }
  if (seg == 0) { othN[pN] = (int)dst; othF[pF] = (int)src; }
  const uint4 c0 = *(const uint4*)((char*)lds + LDSW(orow, seg*32));
  const uint4 c1 = *(const uint4*)((char*)lds + LDSW(orow, seg*32 + 16));
  *(uint4*)(epN + (size_t)pN*DD + seg*16)     = c0;
  *(uint4*)(epN + (size_t)pN*DD + seg*16 + 8) = c1;
  *(uint4*)(epF + (size_t)pF*DD + seg*16)     = c0;
  *(uint4*)(epF + (size_t)pF*DD + seg*16 + 8) = c1;
}

// merged gather with explicit prefetch rotate (round-4-proven pattern):
// next iteration's oth + sequential ep row issue before current proj load.
__global__ __launch_bounds__(256) void k_gather4(const int* __restrict__ staN,
                                                 const int* __restrict__ cntN,
                                                 const int* __restrict__ othN,
                                                 const u16* __restrict__ epN,
                                                 const u16* __restrict__ FpN,
                                                 float* __restrict__ msgN,
                                                 const int* __restrict__ staF,
                                                 const int* __restrict__ cntF,
                                                 const int* __restrict__ othF,
                                                 const u16* __restrict__ epF,
                                                 const u16* __restrict__ NpF,
                                                 float* __restrict__ msgF) {
  const bool isN = blockIdx.x < 12500;
  const int bb = isN ? (int)blockIdx.x : (int)blockIdx.x - 12500;
  const int* __restrict__ sta = isN ? staN : staF;
  const int* __restrict__ cnt = isN ? cntN : cntF;
  const int* __restrict__ oth = isN ? othN : othF;
  const u16* __restrict__ eps = isN ? epN : epF;
  const u16* __restrict__ proj = isN ? FpN : NpF;
  float* __restrict__ msg = isN ? msgN : msgF;

  const int n = bb*4 + (threadIdx.x >> 6);
  const int lane = threadIdx.x & 63;
  const int half = lane >> 5;
  const int lh = lane & 31;          // channel pair {2lh, 2lh+1}
  const int start = sta[n];
  const int end = start + cnt[n];
  float a0 = 0.f, a1 = 0.f;
  int i = start + half;
  int o_cur = 0; u32 ev_cur = 0;
  if (i < end) {
    o_cur = oth[i];
    ev_cur = *(const u32*)(eps + (size_t)i*DD + 2*lh);
  }
  for (; i < end; i += 2) {
    const int o = o_cur; const u32 ev = ev_cur;
    if (i + 2 < end) {
      o_cur = oth[i + 2];
      ev_cur = *(const u32*)(eps + (size_t)(i + 2)*DD + 2*lh);
    }
    const u32 pv = *(const u32*)(proj + (size_t)o*DD + 2*lh);
    a0 += fmaxf(bf2f((u16)(ev & 0xffffu)) + bf2f((u16)(pv & 0xffffu)), 0.f);
    a1 += fmaxf(bf2f((u16)(ev >> 16))     + bf2f((u16)(pv >> 16)),     0.f);
  }
  a0 += __shfl_xor(a0, 32, 64);
  a1 += __shfl_xor(a1, 32, 64);
  if (half == 0)
    *(float2*)(msg + (size_t)n*DD + 2*lh) = make_float2(a0, a1);
}

// MFMA update (round-14 proven)
__global__ __launch_bounds__(256) void k_updm(const float* __restrict__ node,
                                              const float* __restrict__ feat,
                                              const int* __restrict__ cntN,
                                              const int* __restrict__ cntF,
                                              float* msgN, float* msgF,
                                              const u16* __restrict__ Bpk,
                                              const float* __restrict__ bQ,
                                              float* __restrict__ outN,
                                              float* __restrict__ outF) {
  __shared__ char lb[40960];  // A1[0,8K) A2[8K,16K) C1h[16K,24K) C1f[24K,40K)
  const int t = threadIdx.x;
  const bool isN = blockIdx.x < UBLK;
  const int b = isN ? (int)blockIdx.x : (int)blockIdx.x - UBLK;
  const int r0 = b * 64;
  const float* __restrict__ emb = isN ? node : feat;
  const int* __restrict__ cnt = isN ? cntN : cntF;
  float* msgp = isN ? msgN : msgF;
  float* __restrict__ outp = isN ? outN : outF;
  const u16* __restrict__ BQ0 = Bpk + 2*4096;
  const u16* __restrict__ BQ1 = Bpk + 3*4096;
  const u16* __restrict__ BW  = Bpk + (isN ? 4 : 5)*4096;

  #pragma unroll
  for (int i = 0; i < 4; ++i) {
    const int g = i*256 + t;
    const int row = g >> 4;
    const int grow = r0 + row;
    const int q = g & 15;
    float4 v1 = make_float4(0.f, 0.f, 0.f, 0.f), v2 = v1;
    if (grow < 50000) {
      v1 = ((const float4*)(emb + (size_t)grow*DD))[q];
      const float inv = 1.f / fmaxf((float)cnt[grow], 1.f);
      const float4 mm = ((const float4*)(msgp + (size_t)grow*DD))[q];
      v2 = make_float4(mm.x*inv, mm.y*inv, mm.z*inv, mm.w*inv);
    }
    *(uint2*)(lb + LDSW(row, q*8))        = make_uint2(pk2(v1.x,v1.y), pk2(v1.z,v1.w));
    *(uint2*)(lb + 8192 + LDSW(row, q*8)) = make_uint2(pk2(v2.x,v2.y), pk2(v2.z,v2.w));
  }
  __syncthreads();
  const int w = t >> 6, l = t & 63;
  bf16x8 q0f[8], q1f[8];
  #pragma unroll
  for (int f = 0; f < 8; ++f) {
    q0f[f] = *(const bf16x8*)(BQ0 + (f*64 + l)*8);
    q1f[f] = *(const bf16x8*)(BQ1 + (f*64 + l)*8);
  }
  f32x4 acc[4];
  #pragma unroll
  for (int nt = 0; nt < 4; ++nt) {
    const float bb2 = bQ[nt*16 + (l&15)];
    acc[nt] = (f32x4){bb2, bb2, bb2, bb2};
  }
  const int arow = w*16 + (l&15);
  const bf16x8 e0 = *(const bf16x8*)(lb + LDSW(arow, (l>>4)*16));
  const bf16x8 e1 = *(const bf16x8*)(lb + LDSW(arow, 64 + (l>>4)*16));
  const bf16x8 m0 = *(const bf16x8*)(lb + 8192 + LDSW(arow, (l>>4)*16));
  const bf16x8 m1 = *(const bf16x8*)(lb + 8192 + LDSW(arow, 64 + (l>>4)*16));
  #pragma unroll
  for (int nt = 0; nt < 4; ++nt) {
    acc[nt] = __builtin_amdgcn_mfma_f32_16x16x32_bf16(e0, q0f[nt],   acc[nt], 0, 0, 0);
    acc[nt] = __builtin_amdgcn_mfma_f32_16x16x32_bf16(e1, q0f[4+nt], acc[nt], 0, 0, 0);
    acc[nt] = __builtin_amdgcn_mfma_f32_16x16x32_bf16(m0, q1f[nt],   acc[nt], 0, 0, 0);
    acc[nt] = __builtin_amdgcn_mfma_f32_16x16x32_bf16(m1, q1f[4+nt], acc[nt], 0, 0, 0);
  }
  #pragma unroll
  for (int nt = 0; nt < 4; ++nt) {
    #pragma unroll
    for (int r = 0; r < 4; ++r) {
      const int row = w*16 + (l>>4)*4 + r;
      const int col = nt*16 + (l&15);
      const float val = acc[nt][r];
      *(float*)(lb + 24576 + LDSWF(row, col*4)) = val;
      *(u16*)(lb + 16384 + LDSW(row, col*2)) = f2bf(val);
    }
  }
  #pragma unroll
  for (int i = 0; i < 4; ++i) {
    const int row = w*16 + i*4 + (l>>4);
    const int grow = r0 + row;
    if (grow < 50000) {
      const uint4 vv = *(const uint4*)(lb + 24576 + LDSWF(row, (l&15)*16));
      *(uint4*)((u32*)(outp + (size_t)grow*DD) + (l&15)*4) = vv;
    }
  }
  bf16x8 wf[8];
  #pragma unroll
  for (int f = 0; f < 8; ++f)
    wf[f] = *(const bf16x8*)(BW + (f*64 + l)*8);
  f32x4 acc2[4];
  #pragma unroll
  for (int nt = 0; nt < 4; ++nt) acc2[nt] = (f32x4){0.f, 0.f, 0.f, 0.f};
  const bf16x8 c0 = *(const bf16x8*)(lb + 16384 + LDSW(arow, (l>>4)*16));
  const bf16x8 c1 = *(const bf16x8*)(lb + 16384 + LDSW(arow, 64 + (l>>4)*16));
  #pragma unroll
  for (int nt = 0; nt < 4; ++nt) {
    acc2[nt] = __builtin_amdgcn_mfma_f32_16x16x32_bf16(c0, wf[nt],   acc2[nt], 0, 0, 0);
    acc2[nt] = __builtin_amdgcn_mfma_f32_16x16x32_bf16(c1, wf[4+nt], acc2[nt], 0, 0, 0);
  }
  #pragma unroll
  for (int nt = 0; nt < 4; ++nt) {
    #pragma unroll
    for (int r = 0; r < 4; ++r) {
      const int row = w*16 + (l>>4)*4 + r;
      const int col = nt*16 + (l&15);
      *(u16*)(lb + LDSW(row, col*2)) = f2bf(acc2[nt][r]);
    }
  }
  #pragma unroll
  for (int i = 0; i < 2; ++i) {
    const int row = w*16 + i*8 + (l>>3);
    const int grow = r0 + row;
    if (grow < 50000) {
      const uint4 vv = *(const uint4*)(lb + LDSW(row, (l&7)*16));
      *(uint4*)((u16*)(msgp + (size_t)grow*DD) + (l&7)*8) = vv;
    }
  }
}

// MFMA edge_out; NOw/FOw gather rows hoisted to kernel start (latency hidden
// under staging + MFMA + transpose).
__global__ __launch_bounds__(256) void k_eoutm(const float* __restrict__ eemb,
                                               const u32* __restrict__ eidx,
                                               const u16* __restrict__ BpkW,
                                               const float* __restrict__ bW,
                                               const u16* __restrict__ NOw,
                                               const u16* __restrict__ FOw,
                                               float* __restrict__ outp,
                                               const int* __restrict__ flags) {
  __shared__ u16 lds[4096];
  const int t = threadIdx.x;
  const int e0 = blockIdx.x * 64;
  const int w = t >> 6, l = t & 63;
  const int lr = l >> 2, seg = l & 3;
  const int orow = w*16 + lr;
  const int e = e0 + orow;
  const int I64 = flags[0];
  const u32 src = eidx_at(eidx, (size_t)e, I64);
  const u32 dst = eidx_at(eidx, (size_t)NE + e, I64);
  // hoisted random gathers (L2/L3) — independent of all MFMA work below
  const uint4 vn0 = *(const uint4*)(NOw + (size_t)src*128 + seg*16);
  const uint4 vn1 = *(const uint4*)(NOw + (size_t)src*128 + seg*16 + 8);
  const uint4 vf0 = *(const uint4*)(FOw + (size_t)dst*128 + seg*16);
  const uint4 vf1 = *(const uint4*)(FOw + (size_t)dst*128 + seg*16 + 8);

  #pragma unroll
  for (int i = 0; i < 4; ++i) {
    const int g = i*256 + t;
    const float4 v = ((const float4*)(eemb + (size_t)e0*DD))[g];
    const int row = g >> 4;
    const int b   = (g & 15) * 8;
    *(uint2*)((char*)lds + LDSW(row, b)) = make_uint2(pk2(v.x, v.y), pk2(v.z, v.w));
  }
  __syncthreads();
  bf16x8 bf[8];
  #pragma unroll
  for (int f = 0; f < 8; ++f)
    bf[f] = *(const bf16x8*)(BpkW + (f*64 + l)*8);
  f32x4 acc[4];
  #pragma unroll
  for (int nt = 0; nt < 4; ++nt) {
    const float b = bW[nt*16 + (l&15)];
    acc[nt] = (f32x4){b, b, b, b};
  }
  const int arow = w*16 + (l&15);
  const bf16x8 a0 = *(const bf16x8*)((char*)lds + LDSW(arow, (l>>4)*16));
  const bf16x8 a1 = *(const bf16x8*)((char*)lds + LDSW(arow, 64 + (l>>4)*16));
  #pragma unroll
  for (int nt = 0; nt < 4; ++nt) {
    acc[nt] = __builtin_amdgcn_mfma_f32_16x16x32_bf16(a0, bf[nt],     acc[nt], 0, 0, 0);
    acc[nt] = __builtin_amdgcn_mfma_f32_16x16x32_bf16(a1, bf[4 + nt], acc[nt], 0, 0, 0);
  }
  #pragma unroll
  for (int nt = 0; nt < 4; ++nt) {
    #pragma unroll
    for (int r = 0; r < 4; ++r) {
      const int row = w*16 + (l>>4)*4 + r;
      const int col = nt*16 + (l&15);
      *(u16*)((char*)lds + LDSW(row, col*2)) = f2bf(acc[nt][r]);
    }
  }
  const uint4 c0 = *(const uint4*)((char*)lds + LDSW(orow, seg*32));
  const uint4 c1 = *(const uint4*)((char*)lds + LDSW(orow, seg*32 + 16));
  float r[16];
  {
    const uint4 v = c0;
    r[0]=bf2f((u16)(v.x&0xffffu)); r[1]=bf2f((u16)(v.x>>16));
    r[2]=bf2f((u16)(v.y&0xffffu)); r[3]=bf2f((u16)(v.y>>16));
    r[4]=bf2f((u16)(v.z&0xffffu)); r[5]=bf2f((u16)(v.z>>16));
    r[6]=bf2f((u16)(v.w&0xffffu)); r[7]=bf2f((u16)(v.w>>16));
  }
  {
    const uint4 v = c1;
    r[8]=bf2f((u16)(v.x&0xffffu));  r[9]=bf2f((u16)(v.x>>16));
    r[10]=bf2f((u16)(v.y&0xffffu)); r[11]=bf2f((u16)(v.y>>16));
    r[12]=bf2f((u16)(v.z&0xffffu)); r[13]=bf2f((u16)(v.z>>16));
    r[14]=bf2f((u16)(v.w&0xffffu)); r[15]=bf2f((u16)(v.w>>16));
  }
  r[0]+=bf2f((u16)(vn0.x&0xffffu))+bf2f((u16)(vf0.x&0xffffu));
  r[1]+=bf2f((u16)(vn0.x>>16))+bf2f((u16)(vf0.x>>16));
  r[2]+=bf2f((u16)(vn0.y&0xffffu))+bf2f((u16)(vf0.y&0xffffu));
  r[3]+=bf2f((u16)(vn0.y>>16))+bf2f((u16)(vf0.y>>16));
  r[4]+=bf2f((u16)(vn0.z&0xffffu))+bf2f((u16)(vf0.z&0xffffu));
  r[5]+=bf2f((u16)(vn0.z>>16))+bf2f((u16)(vf0.z>>16));
  r[6]+=bf2f((u16)(vn0.w&0xffffu))+bf2f((u16)(vf0.w&0xffffu));
  r[7]+=bf2f((u16)(vn0.w>>16))+bf2f((u16)(vf0.w>>16));
  r[8]+=bf2f((u16)(vn1.x&0xffffu))+bf2f((u16)(vf1.x&0xffffu));
  r[9]+=bf2f((u16)(vn1.x>>16))+bf2f((u16)(vf1.x>>16));
  r[10]+=bf2f((u16)(vn1.y&0xffffu))+bf2f((u16)(vf1.y&0xffffu));
  r[11]+=bf2f((u16)(vn1.y>>16))+bf2f((u16)(vf1.y>>16));
  r[12]+=bf2f((u16)(vn1.z&0xffffu))+bf2f((u16)(vf1.z&0xffffu));
  r[13]+=bf2f((u16)(vn1.z>>16))+bf2f((u16)(vf1.z>>16));
  r[14]+=bf2f((u16)(vn1.w&0xffffu))+bf2f((u16)(vf1.w&0xffffu));
  r[15]+=bf2f((u16)(vn1.w>>16))+bf2f((u16)(vf1.w>>16));
  float4* o4 = (float4*)(outp + (size_t)e*DD + seg*16);
  #pragma unroll
  for (int i = 0; i < 4; ++i)
    o4[i] = make_float4(r[4*i], r[4*i+1], r[4*i+2], r[4*i+3]);
}

extern "C" void kernel_launch(void* const* d_in, const int* in_sizes, int n_in,
                              void* d_out, int out_size, void* d_ws, size_t ws_size,
                              hipStream_t stream) {
  if (ws_size < (size_t)WS_FLOATS * 4) return;
  const float* node = (const float*)d_in[0];
  const float* eemb = (const float*)d_in[1];
  const float* feat = (const float*)d_in[2];
  const u32*   eidx = (const u32*)d_in[3];
  const float* P  = (const float*)d_in[4];
  const float* bP = (const float*)d_in[5];
  const float* Q  = (const float*)d_in[6];
  const float* bQ = (const float*)d_in[7];
  const float* W  = (const float*)d_in[8];
  const float* bW = (const float*)d_in[9];
  float* wsf = (float*)d_ws;
  int*   wsi = (int*)d_ws;
  float* out = (float*)d_out;

  u16* Fp_h = (u16*)out;
  u16* epN_h = (u16*)(out + (size_t)ND*DD);
  u16* epF_h = epN_h + (size_t)NE*DD;
  u16* Np_h = (u16*)(out + (size_t)(ND + NE)*DD);
  float* msgN = wsf + OFF_MSGN;
  float* msgF = wsf + OFF_MSGF;
  int* rankN = (int*)(wsf + OFF_MSGN);  // overlays msgN start; dead after k_epm
  int* rankF = rankN + NE;
  u16* Bpk = (u16*)(wsf + OFF_BPK);     // [P1|W0|Q0|Q1|W1|W2] x 4096

  k_pre<<<488, 256, 0, stream>>>(eidx, wsi + OFF_FLAGS, wsi + OFF_CNTN,
                                 P + 64*DD, W, Q, Q + 64*DD, W + 64*DD, W + 128*DD, Bpk);
  k_hist2<<<EBLK, 256, 0, stream>>>(eidx, wsi + OFF_CNTN, wsi + OFF_CNTF,
                                    rankN, rankF, wsi + OFF_FLAGS);
  k_scan<<<2, 1024, 0, stream>>>(wsi + OFF_CNTN, wsi + OFF_STAN);
  k_proj2<<<2*NBLK, 256, 0, stream>>>(feat, node, P, Fp_h, Np_h);
  k_epm<<<12500, 256, 0, stream>>>(eemb, eidx, Bpk, bP,
                                   wsi + OFF_STAN, wsi + OFF_STAF,
                                   rankN, rankF,
                                   wsi + OFF_OTHN, wsi + OFF_OTHF,
                                   epN_h, epF_h, wsi + OFF_FLAGS);
  k_gather4<<<25000, 256, 0, stream>>>(wsi + OFF_STAN, wsi + OFF_CNTN, wsi + OFF_OTHN,
                                       epN_h, Fp_h, msgN,
                                       wsi + OFF_STAF, wsi + OFF_CNTF, wsi + OFF_OTHF,
                                       epF_h, Np_h, msgF);
  k_updm<<<2*UBLK, 256, 0, stream>>>(node, feat, wsi + OFF_CNTN, wsi + OFF_CNTF,
                                     msgN, msgF, Bpk, bQ,
                                     out, out + (size_t)(ND + NE)*DD);
  k_eoutm<<<12500, 256, 0, stream>>>(eemb, eidx, Bpk + 4096, bW,
                                     (const u16*)msgN, (const u16*)msgF,
                                     out + (size_t)ND*DD, wsi + OFF_FLAGS);
}

// Round 19
// 509.616 us; speedup vs baseline: 1.0238x; 1.0238x over previous
//
#include <hip/hip_runtime.h>

typedef unsigned int u32;
typedef unsigned short u16;
using bf16x8 = __attribute__((ext_vector_type(8))) short;
using f32x4  = __attribute__((ext_vector_type(4))) float;

#define ND 50000
#define NF 50000
#define NE 800000
#define DD 64
#define NBLK 196   // ceil(50000/256)
#define EBLK 3125  // 800000/256
#define UBLK 782   // ceil(50000/64)

// ---- ws float-index layout ----
#define OFF_FLAGS 0                        // [0] = idx-is-int64
#define OFF_CNTN  64
#define OFF_CNTF  (OFF_CNTN + 50000)
#define OFF_STAN  (OFF_CNTF + 50000)       // start offsets (never mutated after scan)
#define OFF_STAF  (OFF_STAN + 50000)
#define OFF_OTHN  (OFF_STAF + 50000)
#define OFF_OTHF  (OFF_OTHN + 800000)
#define OFF_MSGN  (OFF_OTHF + 800000)      // first 1.6M floats: rankN/rankF (dead after k_epm)
#define OFF_MSGF  (OFF_MSGN + 3200000)
#define OFF_BPK   (OFF_MSGF + 3200000)     // 12288 floats: 6*4096 bf16 B-frags
                                           // [P1 | W0 | Q0 | Q1 | W1 | W2]
#define WS_FLOATS (OFF_BPK + 12288)

__device__ __forceinline__ u16 f2bf(float x){ union{u32 u;float f;}v; v.f=x; u32 r=v.u+0x7fffu+((v.u>>16)&1u); return (u16)(r>>16); }
__device__ __forceinline__ float bf2f(u16 h){ union{u32 u;float f;}v; v.u=((u32)h)<<16; return v.f; }
__device__ __forceinline__ u32 pk2(float a,float b){ return (u32)f2bf(a) | ((u32)f2bf(b)<<16); }

// vectorized index fetch (int64 path loads one uint2 instead of two stride-2 words)
__device__ __forceinline__ u32 eidx_at(const u32* __restrict__ eidx, size_t i, int I64) {
  if (I64) return ((const uint2*)eidx)[i].x;
  return eidx[i];
}

// swizzled LDS byte offset for 128B bf16 rows / 256B fp32 rows
#define LDSW(row, b)  ((row)*128 + ((b) ^ (((row)&7)<<4)))
#define LDSWF(row, b) ((row)*256 + ((b) ^ (((row)&3)<<6)))

// merged prologue: blocks [0,391) zero cnt; block 391 detects dtype; [392,488) pack B-frags
__global__ __launch_bounds__(256) void k_pre(const u32* __restrict__ idxw,
                                             int* __restrict__ flags,
                                             int* __restrict__ cnt,        // 100000 ints
                                             const float* __restrict__ P1,
                                             const float* __restrict__ W0,
                                             const float* __restrict__ Q0,
                                             const float* __restrict__ Q1,
                                             const float* __restrict__ W1,
                                             const float* __restrict__ W2,
                                             u16* __restrict__ Bpk) {
  __shared__ int cn;
  const int b = blockIdx.x;
  if (b < 391) {
    const int i = b*256 + threadIdx.x;
    if (i < 100000) cnt[i] = 0;
  } else if (b == 391) {
    if (threadIdx.x == 0) cn = 0;
    __syncthreads();
    int c = 0;
    for (int k = 0; k < 16; ++k)
      c += (idxw[2*(threadIdx.x + k*256) + 1] != 0u) ? 1 : 0;
    atomicAdd(&cn, c);
    __syncthreads();
    if (threadIdx.x == 0) flags[0] = (cn == 0) ? 1 : 0;
  } else {
    const int v = (b - 392)*256 + threadIdx.x;   // 0..24575
    const int mi = v >> 12;
    const int vv = v & 4095;
    const int f = vv >> 9, rem = vv & 511;
    const int lane = rem >> 3, j = rem & 7;
    const int kk = f >> 2, nt = f & 3;
    const int k = kk*32 + (lane>>4)*8 + j;
    const int col = nt*16 + (lane&15);
    const float* __restrict__ S = (mi==0) ? P1 : (mi==1) ? W0 : (mi==2) ? Q0
                                : (mi==3) ? Q1 : (mi==4) ? W1 : W2;
    Bpk[v] = f2bf(S[k*64 + col]);
  }
}

// histogram + per-edge rank capture
__global__ __launch_bounds__(256) void k_hist2(const u32* __restrict__ eidx,
                                               int* __restrict__ cntN,
                                               int* __restrict__ cntF,
                                               int* __restrict__ rankN,
                                               int* __restrict__ rankF,
                                               const int* __restrict__ flags) {
  const int e = blockIdx.x*256 + threadIdx.x;
  const int I64 = flags[0];
  const u32 src = eidx_at(eidx, (size_t)e, I64);
  const u32 dst = eidx_at(eidx, (size_t)NE + e, I64);
  rankN[e] = atomicAdd(cntN + src, 1);
  rankF[e] = atomicAdd(cntF + dst, 1);
}

__global__ __launch_bounds__(1024) void k_scan(const int* __restrict__ cnt,
                                               int* __restrict__ sta) {
  const int base = blockIdx.x * 50000;
  const int t = threadIdx.x;
  __shared__ int part[1024];
  int local[49];
  int s = 0;
  const int start = t * 49;
  #pragma unroll
  for (int j = 0; j < 49; ++j) {
    const int idx = start + j;
    const int v = (idx < 50000) ? cnt[base + idx] : 0;
    local[j] = s;
    s += v;
  }
  part[t] = s;
  __syncthreads();
  for (int off = 1; off < 1024; off <<= 1) {
    int v = 0;
    if (t >= off) v = part[t - off];
    __syncthreads();
    if (t >= off) part[t] += v;
    __syncthreads();
  }
  const int bv = (t > 0) ? part[t - 1] : 0;
  #pragma unroll
  for (int j = 0; j < 49; ++j) {
    const int idx = start + j;
    if (idx < 50000) sta[base + idx] = bv + local[j];
  }
}

// merged proj: blocks [0,196) feat->Fp, [196,392) node->Np
__global__ __launch_bounds__(256) void k_proj2(const float* __restrict__ feat,
                                               const float* __restrict__ node,
                                               const float* __restrict__ wt,
                                               u16* __restrict__ Fp,
                                               u16* __restrict__ Np) {
  const bool isF = blockIdx.x < NBLK;
  const int row = (isF ? (int)blockIdx.x : (int)blockIdx.x - NBLK)*256 + threadIdx.x;
  if (row >= 50000) return;
  const float* __restrict__ emb = isF ? feat : node;
  u16* __restrict__ outp = isF ? Fp : Np;
  float acc[DD];
  #pragma unroll
  for (int c = 0; c < DD; ++c) acc[c] = 0.f;
  #pragma unroll 4
  for (int k4 = 0; k4 < 16; ++k4) {
    const float4 v = *(const float4*)(emb + (size_t)row*DD + k4*4);
    const float f[4] = {v.x, v.y, v.z, v.w};
    const float* __restrict__ wr = wt + k4*4*DD;
    #pragma unroll
    for (int c = 0; c < DD; ++c) {
      float a = acc[c];
      #pragma unroll
      for (int j = 0; j < 4; ++j) a = fmaf(f[j], wr[j*DD + c], a);
      acc[c] = a;
    }
  }
  uint4 s[8]; u32* sw = (u32*)s;
  #pragma unroll
  for (int i = 0; i < 32; ++i) sw[i] = pk2(acc[2*i], acc[2*i+1]);
  uint4* o4 = (uint4*)(outp + (size_t)row*DD);
  #pragma unroll
  for (int i = 0; i < 8; ++i) o4[i] = s[i];
}

// MFMA ep: X(64x64)@P1 + bP -> bf16 rows scattered to CSR slots (round-15 proven)
__global__ __launch_bounds__(256) void k_epm(const float* __restrict__ eemb,
                                             const u32* __restrict__ eidx,
                                             const u16* __restrict__ Bpk,
                                             const float* __restrict__ bP,
                                             const int* __restrict__ staN,
                                             const int* __restrict__ staF,
                                             const int* __restrict__ rankN,
                                             const int* __restrict__ rankF,
                                             int* __restrict__ othN,
                                             int* __restrict__ othF,
                                             u16* __restrict__ epN,
                                             u16* __restrict__ epF,
                                             const int* __restrict__ flags) {
  __shared__ u16 lds[4096];
  const int t = threadIdx.x;
  const int e0 = blockIdx.x * 64;
  #pragma unroll
  for (int i = 0; i < 4; ++i) {
    const int g = i*256 + t;
    const float4 v = ((const float4*)(eemb + (size_t)e0*DD))[g];
    const int row = g >> 4;
    const int b   = (g & 15) * 8;
    *(uint2*)((char*)lds + LDSW(row, b)) = make_uint2(pk2(v.x, v.y), pk2(v.z, v.w));
  }
  __syncthreads();
  const int w = t >> 6, l = t & 63;
  bf16x8 bf[8];
  #pragma unroll
  for (int f = 0; f < 8; ++f)
    bf[f] = *(const bf16x8*)(Bpk + (f*64 + l)*8);
  f32x4 acc[4];
  #pragma unroll
  for (int nt = 0; nt < 4; ++nt) {
    const float b = bP[nt*16 + (l&15)];
    acc[nt] = (f32x4){b, b, b, b};
  }
  const int arow = w*16 + (l&15);
  const bf16x8 a0 = *(const bf16x8*)((char*)lds + LDSW(arow, (l>>4)*16));
  const bf16x8 a1 = *(const bf16x8*)((char*)lds + LDSW(arow, 64 + (l>>4)*16));
  #pragma unroll
  for (int nt = 0; nt < 4; ++nt) {
    acc[nt] = __builtin_amdgcn_mfma_f32_16x16x32_bf16(a0, bf[nt],     acc[nt], 0, 0, 0);
    acc[nt] = __builtin_amdgcn_mfma_f32_16x16x32_bf16(a1, bf[4 + nt], acc[nt], 0, 0, 0);
  }
  #pragma unroll
  for (int nt = 0; nt < 4; ++nt) {
    #pragma unroll
    for (int r = 0; r < 4; ++r) {
      const int row = w*16 + (l>>4)*4 + r;
      const int col = nt*16 + (l&15);
      *(u16*)((char*)lds + LDSW(row, col*2)) = f2bf(acc[nt][r]);
    }
  }
  const int lr = l >> 2, seg = l & 3;
  const int row = w*16 + lr;
  const int e = e0 + row;
  const int I64 = flags[0];
  const u32 src = eidx_at(eidx, (size_t)e, I64);
  const u32 dst = eidx_at(eidx, (size_t)NE + e, I64);
  const int pN = staN[src] + rankN[e];
  const int pF = staF[dst] + rankF[e];
  if (seg == 0) { othN[pN] = (int)dst; othF[pF] = (int)src; }
  const uint4 c0 = *(const uint4*)((char*)lds + LDSW(row, seg*32));
  const uint4 c1 = *(const uint4*)((char*)lds + LDSW(row, seg*32 + 16));
  *(uint4*)(epN + (size_t)pN*DD + seg*16)     = c0;
  *(uint4*)(epN + (size_t)pN*DD + seg*16 + 8) = c1;
  *(uint4*)(epF + (size_t)pF*DD + seg*16)     = c0;
  *(uint4*)(epF + (size_t)pF*DD + seg*16 + 8) = c1;
}

// merged gather: blocks [0,12500) N side, [12500,25000) F side.
// half-wave per edge, u32 (2 channels) per lane; combine via shfl_xor(32).
__global__ __launch_bounds__(256) void k_gather4(const int* __restrict__ staN,
                                                 const int* __restrict__ cntN,
                                                 const int* __restrict__ othN,
                                                 const u16* __restrict__ epN,
                                                 const u16* __restrict__ FpN,
                                                 float* __restrict__ msgN,
                                                 const int* __restrict__ staF,
                                                 const int* __restrict__ cntF,
                                                 const int* __restrict__ othF,
                                                 const u16* __restrict__ epF,
                                                 const u16* __restrict__ NpF,
                                                 float* __restrict__ msgF) {
  const bool isN = blockIdx.x < 12500;
  const int bb = isN ? (int)blockIdx.x : (int)blockIdx.x - 12500;
  const int* __restrict__ sta = isN ? staN : staF;
  const int* __restrict__ cnt = isN ? cntN : cntF;
  const int* __restrict__ oth = isN ? othN : othF;
  const u16* __restrict__ eps = isN ? epN : epF;
  const u16* __restrict__ proj = isN ? FpN : NpF;
  float* __restrict__ msg = isN ? msgN : msgF;

  const int n = bb*4 + (threadIdx.x >> 6);
  const int lane = threadIdx.x & 63;
  const int half = lane >> 5;
  const int lh = lane & 31;          // channel pair {2lh, 2lh+1}
  const int start = sta[n];
  const int end = start + cnt[n];
  float a0 = 0.f, a1 = 0.f;
  #pragma unroll 2
  for (int i = start + half; i < end; i += 2) {
    const int o = oth[i];
    const u32 ev = *(const u32*)(eps  + (size_t)i*DD + 2*lh);
    const u32 pv = *(const u32*)(proj + (size_t)o*DD + 2*lh);
    a0 += fmaxf(bf2f((u16)(ev & 0xffffu)) + bf2f((u16)(pv & 0xffffu)), 0.f);
    a1 += fmaxf(bf2f((u16)(ev >> 16))     + bf2f((u16)(pv >> 16)),     0.f);
  }
  a0 += __shfl_xor(a0, 32, 64);
  a1 += __shfl_xor(a1, 32, 64);
  if (half == 0)
    *(float2*)(msg + (size_t)n*DD + 2*lh) = make_float2(a0, a1);
}

// MFMA update (round-14 proven)
__global__ __launch_bounds__(256) void k_updm(const float* __restrict__ node,
                                              const float* __restrict__ feat,
                                              const int* __restrict__ cntN,
                                              const int* __restrict__ cntF,
                                              float* msgN, float* msgF,
                                              const u16* __restrict__ Bpk,
                                              const float* __restrict__ bQ,
                                              float* __restrict__ outN,
                                              float* __restrict__ outF) {
  __shared__ char lb[40960];  // A1[0,8K) A2[8K,16K) C1h[16K,24K) C1f[24K,40K)
  const int t = threadIdx.x;
  const bool isN = blockIdx.x < UBLK;
  const int b = isN ? (int)blockIdx.x : (int)blockIdx.x - UBLK;
  const int r0 = b * 64;
  const float* __restrict__ emb = isN ? node : feat;
  const int* __restrict__ cnt = isN ? cntN : cntF;
  float* msgp = isN ? msgN : msgF;
  float* __restrict__ outp = isN ? outN : outF;
  const u16* __restrict__ BQ0 = Bpk + 2*4096;
  const u16* __restrict__ BQ1 = Bpk + 3*4096;
  const u16* __restrict__ BW  = Bpk + (isN ? 4 : 5)*4096;

  #pragma unroll
  for (int i = 0; i < 4; ++i) {
    const int g = i*256 + t;
    const int row = g >> 4;
    const int grow = r0 + row;
    const int q = g & 15;
    float4 v1 = make_float4(0.f, 0.f, 0.f, 0.f), v2 = v1;
    if (grow < 50000) {
      v1 = ((const float4*)(emb + (size_t)grow*DD))[q];
      const float inv = 1.f / fmaxf((float)cnt[grow], 1.f);
      const float4 mm = ((const float4*)(msgp + (size_t)grow*DD))[q];
      v2 = make_float4(mm.x*inv, mm.y*inv, mm.z*inv, mm.w*inv);
    }
    *(uint2*)(lb + LDSW(row, q*8))        = make_uint2(pk2(v1.x,v1.y), pk2(v1.z,v1.w));
    *(uint2*)(lb + 8192 + LDSW(row, q*8)) = make_uint2(pk2(v2.x,v2.y), pk2(v2.z,v2.w));
  }
  __syncthreads();
  const int w = t >> 6, l = t & 63;
  bf16x8 q0f[8], q1f[8];
  #pragma unroll
  for (int f = 0; f < 8; ++f) {
    q0f[f] = *(const bf16x8*)(BQ0 + (f*64 + l)*8);
    q1f[f] = *(const bf16x8*)(BQ1 + (f*64 + l)*8);
  }
  f32x4 acc[4];
  #pragma unroll
  for (int nt = 0; nt < 4; ++nt) {
    const float bb2 = bQ[nt*16 + (l&15)];
    acc[nt] = (f32x4){bb2, bb2, bb2, bb2};
  }
  const int arow = w*16 + (l&15);
  const bf16x8 e0 = *(const bf16x8*)(lb + LDSW(arow, (l>>4)*16));
  const bf16x8 e1 = *(const bf16x8*)(lb + LDSW(arow, 64 + (l>>4)*16));
  const bf16x8 m0 = *(const bf16x8*)(lb + 8192 + LDSW(arow, (l>>4)*16));
  const bf16x8 m1 = *(const bf16x8*)(lb + 8192 + LDSW(arow, 64 + (l>>4)*16));
  #pragma unroll
  for (int nt = 0; nt < 4; ++nt) {
    acc[nt] = __builtin_amdgcn_mfma_f32_16x16x32_bf16(e0, q0f[nt],   acc[nt], 0, 0, 0);
    acc[nt] = __builtin_amdgcn_mfma_f32_16x16x32_bf16(e1, q0f[4+nt], acc[nt], 0, 0, 0);
    acc[nt] = __builtin_amdgcn_mfma_f32_16x16x32_bf16(m0, q1f[nt],   acc[nt], 0, 0, 0);
    acc[nt] = __builtin_amdgcn_mfma_f32_16x16x32_bf16(m1, q1f[4+nt], acc[nt], 0, 0, 0);
  }
  #pragma unroll
  for (int nt = 0; nt < 4; ++nt) {
    #pragma unroll
    for (int r = 0; r < 4; ++r) {
      const int row = w*16 + (l>>4)*4 + r;
      const int col = nt*16 + (l&15);
      const float val = acc[nt][r];
      *(float*)(lb + 24576 + LDSWF(row, col*4)) = val;
      *(u16*)(lb + 16384 + LDSW(row, col*2)) = f2bf(val);
    }
  }
  #pragma unroll
  for (int i = 0; i < 4; ++i) {
    const int row = w*16 + i*4 + (l>>4);
    const int grow = r0 + row;
    if (grow < 50000) {
      const uint4 vv = *(const uint4*)(lb + 24576 + LDSWF(row, (l&15)*16));
      *(uint4*)((u32*)(outp + (size_t)grow*DD) + (l&15)*4) = vv;
    }
  }
  bf16x8 wf[8];
  #pragma unroll
  for (int f = 0; f < 8; ++f)
    wf[f] = *(const bf16x8*)(BW + (f*64 + l)*8);
  f32x4 acc2[4];
  #pragma unroll
  for (int nt = 0; nt < 4; ++nt) acc2[nt] = (f32x4){0.f, 0.f, 0.f, 0.f};
  const bf16x8 c0 = *(const bf16x8*)(lb + 16384 + LDSW(arow, (l>>4)*16));
  const bf16x8 c1 = *(const bf16x8*)(lb + 16384 + LDSW(arow, 64 + (l>>4)*16));
  #pragma unroll
  for (int nt = 0; nt < 4; ++nt) {
    acc2[nt] = __builtin_amdgcn_mfma_f32_16x16x32_bf16(c0, wf[nt],   acc2[nt], 0, 0, 0);
    acc2[nt] = __builtin_amdgcn_mfma_f32_16x16x32_bf16(c1, wf[4+nt], acc2[nt], 0, 0, 0);
  }
  #pragma unroll
  for (int nt = 0; nt < 4; ++nt) {
    #pragma unroll
    for (int r = 0; r < 4; ++r) {
      const int row = w*16 + (l>>4)*4 + r;
      const int col = nt*16 + (l&15);
      *(u16*)(lb + LDSW(row, col*2)) = f2bf(acc2[nt][r]);
    }
  }
  #pragma unroll
  for (int i = 0; i < 2; ++i) {
    const int row = w*16 + i*8 + (l>>3);
    const int grow = r0 + row;
    if (grow < 50000) {
      const uint4 vv = *(const uint4*)(lb + LDSW(row, (l&7)*16));
      *(uint4*)((u16*)(msgp + (size_t)grow*DD) + (l&7)*8) = vv;
    }
  }
}

// MFMA edge_out (round-13 proven)
__global__ __launch_bounds__(256) void k_eoutm(const float* __restrict__ eemb,
                                               const u32* __restrict__ eidx,
                                               const u16* __restrict__ BpkW,
                                               const float* __restrict__ bW,
                                               const u16* __restrict__ NOw,
                                               const u16* __restrict__ FOw,
                                               float* __restrict__ outp,
                                               const int* __restrict__ flags) {
  __shared__ u16 lds[4096];
  const int t = threadIdx.x;
  const int e0 = blockIdx.x * 64;
  #pragma unroll
  for (int i = 0; i < 4; ++i) {
    const int g = i*256 + t;
    const float4 v = ((const float4*)(eemb + (size_t)e0*DD))[g];
    const int row = g >> 4;
    const int b   = (g & 15) * 8;
    *(uint2*)((char*)lds + LDSW(row, b)) = make_uint2(pk2(v.x, v.y), pk2(v.z, v.w));
  }
  __syncthreads();
  const int w = t >> 6, l = t & 63;
  bf16x8 bf[8];
  #pragma unroll
  for (int f = 0; f < 8; ++f)
    bf[f] = *(const bf16x8*)(BpkW + (f*64 + l)*8);
  f32x4 acc[4];
  #pragma unroll
  for (int nt = 0; nt < 4; ++nt) {
    const float b = bW[nt*16 + (l&15)];
    acc[nt] = (f32x4){b, b, b, b};
  }
  const int arow = w*16 + (l&15);
  const bf16x8 a0 = *(const bf16x8*)((char*)lds + LDSW(arow, (l>>4)*16));
  const bf16x8 a1 = *(const bf16x8*)((char*)lds + LDSW(arow, 64 + (l>>4)*16));
  #pragma unroll
  for (int nt = 0; nt < 4; ++nt) {
    acc[nt] = __builtin_amdgcn_mfma_f32_16x16x32_bf16(a0, bf[nt],     acc[nt], 0, 0, 0);
    acc[nt] = __builtin_amdgcn_mfma_f32_16x16x32_bf16(a1, bf[4 + nt], acc[nt], 0, 0, 0);
  }
  #pragma unroll
  for (int nt = 0; nt < 4; ++nt) {
    #pragma unroll
    for (int r = 0; r < 4; ++r) {
      const int row = w*16 + (l>>4)*4 + r;
      const int col = nt*16 + (l&15);
      *(u16*)((char*)lds + LDSW(row, col*2)) = f2bf(acc[nt][r]);
    }
  }
  const int lr = l >> 2, seg = l & 3;
  const int row = w*16 + lr;
  const int e = e0 + row;
  const int I64 = flags[0];
  const u32 src = eidx_at(eidx, (size_t)e, I64);
  const u32 dst = eidx_at(eidx, (size_t)NE + e, I64);
  const uint4 c0 = *(const uint4*)((char*)lds + LDSW(row, seg*32));
  const uint4 c1 = *(const uint4*)((char*)lds + LDSW(row, seg*32 + 16));
  float r[16];
  {
    const uint4 v = c0;
    r[0]=bf2f((u16)(v.x&0xffffu)); r[1]=bf2f((u16)(v.x>>16));
    r[2]=bf2f((u16)(v.y&0xffffu)); r[3]=bf2f((u16)(v.y>>16));
    r[4]=bf2f((u16)(v.z&0xffffu)); r[5]=bf2f((u16)(v.z>>16));
    r[6]=bf2f((u16)(v.w&0xffffu)); r[7]=bf2f((u16)(v.w>>16));
  }
  {
    const uint4 v = c1;
    r[8]=bf2f((u16)(v.x&0xffffu));  r[9]=bf2f((u16)(v.x>>16));
    r[10]=bf2f((u16)(v.y&0xffffu)); r[11]=bf2f((u16)(v.y>>16));
    r[12]=bf2f((u16)(v.z&0xffffu)); r[13]=bf2f((u16)(v.z>>16));
    r[14]=bf2f((u16)(v.w&0xffffu)); r[15]=bf2f((u16)(v.w>>16));
  }
  #pragma unroll
  for (int half = 0; half < 2; ++half) {
    const uint4 vn = *(const uint4*)(NOw + (size_t)src*128 + seg*16 + half*8);
    const uint4 vf = *(const uint4*)(FOw + (size_t)dst*128 + seg*16 + half*8);
    float* rr = r + half*8;
    rr[0]+=bf2f((u16)(vn.x&0xffffu))+bf2f((u16)(vf.x&0xffffu));
    rr[1]+=bf2f((u16)(vn.x>>16))+bf2f((u16)(vf.x>>16));
    rr[2]+=bf2f((u16)(vn.y&0xffffu))+bf2f((u16)(vf.y&0xffffu));
    rr[3]+=bf2f((u16)(vn.y>>16))+bf2f((u16)(vf.y>>16));
    rr[4]+=bf2f((u16)(vn.z&0xffffu))+bf2f((u16)(vf.z&0xffffu));
    rr[5]+=bf2f((u16)(vn.z>>16))+bf2f((u16)(vf.z>>16));
    rr[6]+=bf2f((u16)(vn.w&0xffffu))+bf2f((u16)(vf.w&0xffffu));
    rr[7]+=bf2f((u16)(vn.w>>16))+bf2f((u16)(vf.w>>16));
  }
  float4* o4 = (float4*)(outp + (size_t)e*DD + seg*16);
  #pragma unroll
  for (int i = 0; i < 4; ++i)
    o4[i] = make_float4(r[4*i], r[4*i+1], r[4*i+2], r[4*i+3]);
}

extern "C" void kernel_launch(void* const* d_in, const int* in_sizes, int n_in,
                              void* d_out, int out_size, void* d_ws, size_t ws_size,
                              hipStream_t stream) {
  if (ws_size < (size_t)WS_FLOATS * 4) return;
  const float* node = (const float*)d_in[0];
  const float* eemb = (const float*)d_in[1];
  const float* feat = (const float*)d_in[2];
  const u32*   eidx = (const u32*)d_in[3];
  const float* P  = (const float*)d_in[4];
  const float* bP = (const float*)d_in[5];
  const float* Q  = (const float*)d_in[6];
  const float* bQ = (const float*)d_in[7];
  const float* W  = (const float*)d_in[8];
  const float* bW = (const float*)d_in[9];
  float* wsf = (float*)d_ws;
  int*   wsi = (int*)d_ws;
  float* out = (float*)d_out;

  u16* Fp_h = (u16*)out;
  u16* epN_h = (u16*)(out + (size_t)ND*DD);
  u16* epF_h = epN_h + (size_t)NE*DD;
  u16* Np_h = (u16*)(out + (size_t)(ND + NE)*DD);
  float* msgN = wsf + OFF_MSGN;
  float* msgF = wsf + OFF_MSGF;
  int* rankN = (int*)(wsf + OFF_MSGN);  // overlays msgN start; dead after k_epm
  int* rankF = rankN + NE;
  u16* Bpk = (u16*)(wsf + OFF_BPK);     // [P1|W0|Q0|Q1|W1|W2] x 4096

  k_pre<<<488, 256, 0, stream>>>(eidx, wsi + OFF_FLAGS, wsi + OFF_CNTN,
                                 P + 64*DD, W, Q, Q + 64*DD, W + 64*DD, W + 128*DD, Bpk);
  k_hist2<<<EBLK, 256, 0, stream>>>(eidx, wsi + OFF_CNTN, wsi + OFF_CNTF,
                                    rankN, rankF, wsi + OFF_FLAGS);
  k_scan<<<2, 1024, 0, stream>>>(wsi + OFF_CNTN, wsi + OFF_STAN);
  k_proj2<<<2*NBLK, 256, 0, stream>>>(feat, node, P, Fp_h, Np_h);
  k_epm<<<12500, 256, 0, stream>>>(eemb, eidx, Bpk, bP,
                                   wsi + OFF_STAN, wsi + OFF_STAF,
                                   rankN, rankF,
                                   wsi + OFF_OTHN, wsi + OFF_OTHF,
                                   epN_h, epF_h, wsi + OFF_FLAGS);
  k_gather4<<<25000, 256, 0, stream>>>(wsi + OFF_STAN, wsi + OFF_CNTN, wsi + OFF_OTHN,
                                       epN_h, Fp_h, msgN,
                                       wsi + OFF_STAF, wsi + OFF_CNTF, wsi + OFF_OTHF,
                                       epF_h, Np_h, msgF);
  k_updm<<<2*UBLK, 256, 0, stream>>>(node, feat, wsi + OFF_CNTN, wsi + OFF_CNTF,
                                     msgN, msgF, Bpk, bQ,
                                     out, out + (size_t)(ND + NE)*DD);
  k_eoutm<<<12500, 256, 0, stream>>>(eemb, eidx, Bpk + 4096, bW,
                                     (const u16*)msgN, (const u16*)msgF,
                                     out + (size_t)ND*DD, wsi + OFF_FLAGS);
}